// Round 9
// baseline (93.178 us; speedup 1.0000x reference)
//
#include <hip/hip_runtime.h>

#define NT 8
#define ND 16
#define NH 16
#define NW 16
#define NC 32
#define NB 65536
#define NCELLS (5 * 13 * 13)   // span bases: t in 0..4, d/h in 0..12 -> 845

typedef __attribute__((ext_vector_type(8))) _Float16 half8;
typedef __attribute__((ext_vector_type(4))) _Float16 half4;
typedef __attribute__((ext_vector_type(2))) _Float16 half2v;

union H8 {
    half8 v;
    half2v h2[4];
};

// ---- shared span-base logic (must be IDENTICAL in binning + main) ----
template <int N>
__device__ __forceinline__ int span_base(float u) {
    float s = u * (float)(N - 1);
    float fi = fminf(fmaxf(floorf(s), 0.0f), (float)(N - 2));
    int i = (int)fi;
    return (i == 0) ? 0 : ((i == N - 2) ? (N - 4) : (i - 1));
}

// Span-based per-dim setup: span b..b+3 (in-bounds) + 4 weights with the
// linear-extrapolation padding folded in. Validated rounds 3-8 (absmax 7.8e-3).
template <int N>
__device__ __forceinline__ void dim_setup_span(float u, int& b, float w[4]) {
    float s = u * (float)(N - 1);
    float fi = fminf(fmaxf(floorf(s), 0.0f), (float)(N - 2));
    float t = s - fi;
    int i = (int)fi;
    float t2 = t * t, t3 = t2 * t;
    const float c6 = 1.0f / 6.0f;
    float w0 = (1.0f - 3.0f * t + 3.0f * t2 - t3) * c6;
    float w1 = (4.0f - 6.0f * t2 + 3.0f * t3) * c6;
    float w2 = (1.0f + 3.0f * t + 3.0f * t2 - 3.0f * t3) * c6;
    float w3 = t3 * c6;
    if (i == 0) {
        b = 0;
        w[0] = w1 + 2.0f * w0; w[1] = w2 - w0; w[2] = w3; w[3] = 0.0f;
    } else if (i == N - 2) {
        b = N - 4;
        w[0] = 0.0f; w[1] = w0; w[2] = w1 - w3; w[3] = w2 + 2.0f * w3;
    } else {
        b = i - 1;
        w[0] = w0; w[1] = w1; w[2] = w2; w[3] = w3;
    }
}

// f32 grid (4 MiB) -> fp16 grid (2 MiB) in workspace, RNE.
__global__ __launch_bounds__(256) void convert_fp16_kernel(
    const float4* __restrict__ g, half4* __restrict__ hg) {
    int i = blockIdx.x * blockDim.x + threadIdx.x;
    float4 v = g[i];
    half4 h;
    h[0] = (_Float16)v.x;
    h[1] = (_Float16)v.y;
    h[2] = (_Float16)v.z;
    h[3] = (_Float16)v.w;
    hg[i] = h;
}

// ---- binning infrastructure ----
__global__ __launch_bounds__(256) void bin_count_kernel(
    const float4* __restrict__ u4, int* __restrict__ count,
    unsigned* __restrict__ cellrank) {
    int q = blockIdx.x * blockDim.x + threadIdx.x;
    float4 uu = u4[q];
    int bt = span_base<NT>(uu.x);
    int bd = span_base<ND>(uu.y);
    int bh = span_base<NH>(uu.z);
    int cell = (bt * 13 + bd) * 13 + bh;
    unsigned rank = (unsigned)atomicAdd(&count[cell], 1);
    cellrank[q] = ((unsigned)cell << 16) | rank;   // rank <= 65535 always
}

__global__ __launch_bounds__(1024) void scan_kernel(
    const int* __restrict__ count, int* __restrict__ offs) {
    __shared__ int tmp[1024];
    int i = threadIdx.x;
    int v = (i < NCELLS) ? count[i] : 0;
    tmp[i] = v;
    __syncthreads();
    for (int d = 1; d < 1024; d <<= 1) {
        int t = (i >= d) ? tmp[i - d] : 0;
        __syncthreads();
        tmp[i] += t;
        __syncthreads();
    }
    if (i < NCELLS) offs[i] = tmp[i] - v;   // exclusive prefix
}

__global__ __launch_bounds__(256) void scatter_kernel(
    const unsigned* __restrict__ cellrank, const int* __restrict__ offs,
    int* __restrict__ perm) {
    int q = blockIdx.x * blockDim.x + threadIdx.x;
    unsigned cr = cellrank[q];
    int cell = (int)(cr >> 16);
    int rank = (int)(cr & 0xffffu);
    perm[offs[cell] + rank] = q;
}

// ---- main binned kernel ----
// One block per cell. Stage the cell's 4x4x4-row region (64KB fp16, all 16 w)
// into LDS coalesced, then each 16-lane group computes one query from LDS.
// Lane s: w-point s>>2, channels 8*(s&3)..+8 (one ds_read_b128 per (i,j,k)).
__global__ __launch_bounds__(512) void spline4d_binned_kernel(
    const float* __restrict__ u, const uint4* __restrict__ hgrid,
    const int* __restrict__ count, const int* __restrict__ offs,
    const int* __restrict__ perm, float4* __restrict__ out) {
    __shared__ uint4 smem[4096];   // 64 KB

    int bin = blockIdx.x;
    int nq = count[bin];
    int off = offs[bin];
    int bt = bin / 169;
    int r0 = bin - bt * 169;
    int bd = r0 / 13;
    int bh = r0 - bd * 13;

    // stage: 64 rows (i,j,k), each 1KB (16 w-points x 64B) = 4096 uint4
    for (int idx = (int)threadIdx.x; idx < 4096; idx += 512) {
        int lrow = idx >> 6;           // i*16 + j*4 + k
        int chunk = idx & 63;
        int i = lrow >> 4, j = (lrow >> 2) & 3, k = lrow & 3;
        int R = ((bt + i) * ND + (bd + j)) * NH + (bh + k);  // (t,d,h) row id
        smem[idx] = hgrid[R * 64 + chunk];
    }
    __syncthreads();
    if (nq == 0) return;

    const half8* slds = reinterpret_cast<const half8*>(smem);
    int slot = (int)threadIdx.x >> 4;
    int s = (int)threadIdx.x & 15;

    for (int qbase = 0; qbase < nq; qbase += 32) {
        int qi = qbase + slot;
        bool active = qi < nq;
        int q = active ? perm[off + qi] : perm[off];   // safe fallback

        float4 uu = reinterpret_cast<const float4*>(u)[q];

        int xbt, xbd, xbh, bw;
        float wtv[4], wdv[4], whv[4], wwv[4];
        dim_setup_span<NT>(uu.x, xbt, wtv);
        dim_setup_span<ND>(uu.y, xbd, wdv);
        dim_setup_span<NH>(uu.z, xbh, whv);
        dim_setup_span<NW>(uu.w, bw, wwv);
        // by construction xbt==bt, xbd==bd, xbh==bh for active slots

        int wp = s >> 2;
        float wlane = (wp & 2) ? ((wp & 1) ? wwv[3] : wwv[2])
                               : ((wp & 1) ? wwv[1] : wwv[0]);

        half2v whW2[4];
#pragma unroll
        for (int k = 0; k < 4; ++k) {
            _Float16 h = (_Float16)(whv[k] * wlane);
            whW2[k][0] = h;
            whW2[k][1] = h;
        }

        float facc[8];
#pragma unroll
        for (int c = 0; c < 8; ++c) facc[c] = 0.0f;
        half2v a01 = {0, 0}, a23 = {0, 0}, a45 = {0, 0}, a67 = {0, 0};

        int lbase = (bw << 2) + s;   // half8 units within a 1KB row

#pragma unroll
        for (int i = 0; i < 4; ++i) {
#pragma unroll
            for (int j = 0; j < 4; ++j) {
                _Float16 wtdh = (_Float16)(wtv[i] * wdv[j]);
                half2v wtd2 = {wtdh, wtdh};
#pragma unroll
                for (int k = 0; k < 4; ++k) {
                    int lidx = ((i << 4) + (j << 2) + k) * 64 + lbase;
                    H8 P;
                    P.v = slds[lidx];
                    half2v uw = wtd2 * whW2[k];
                    a01 += P.h2[0] * uw;
                    a23 += P.h2[1] * uw;
                    a45 += P.h2[2] * uw;
                    a67 += P.h2[3] * uw;
                }
            }
            if (i == 1 || i == 3) {
                facc[0] += (float)a01[0]; facc[1] += (float)a01[1];
                facc[2] += (float)a23[0]; facc[3] += (float)a23[1];
                facc[4] += (float)a45[0]; facc[5] += (float)a45[1];
                facc[6] += (float)a67[0]; facc[7] += (float)a67[1];
                a01 = (half2v){0, 0}; a23 = (half2v){0, 0};
                a45 = (half2v){0, 0}; a67 = (half2v){0, 0};
            }
        }

        // combine 4 w-points: lanes s, s^4, s^8 share channels 8*(s&3)
#pragma unroll
        for (int c = 0; c < 8; ++c) {
            facc[c] += __shfl_xor(facc[c], 4);
            facc[c] += __shfl_xor(facc[c], 8);
        }

        if (active && s < 4) {
            out[q * 8 + s * 2] = make_float4(facc[0], facc[1], facc[2], facc[3]);
            out[q * 8 + s * 2 + 1] =
                make_float4(facc[4], facc[5], facc[6], facc[7]);
        }
    }
}

// ---- fallback: round-6 direct-gather fp16 kernel (passed, 52.5us) ----
__global__ __launch_bounds__(256) void spline4d_fp16_kernel(
    const float* __restrict__ u, const half8* __restrict__ grid,
    float4* __restrict__ out) {
    int tid = blockIdx.x * blockDim.x + threadIdx.x;
    int q = tid >> 4;
    int s = tid & 15;

    float4 uu = reinterpret_cast<const float4*>(u)[q];

    int bt, bd, bh, bw;
    float wtv[4], wdv[4], whv[4], wwv[4];
    dim_setup_span<NT>(uu.x, bt, wtv);
    dim_setup_span<ND>(uu.y, bd, wdv);
    dim_setup_span<NH>(uu.z, bh, whv);
    dim_setup_span<NW>(uu.w, bw, wwv);

    int wp = s >> 2;
    float wlane = (wp & 2) ? ((wp & 1) ? wwv[3] : wwv[2])
                           : ((wp & 1) ? wwv[1] : wwv[0]);

    half2v whW2[4];
#pragma unroll
    for (int k = 0; k < 4; ++k) {
        _Float16 h = (_Float16)(whv[k] * wlane);
        whW2[k][0] = h;
        whW2[k][1] = h;
    }

    int base = ((((bt * ND + bd) * NH + bh) * NW + bw) << 2) + s;

    float facc[8];
#pragma unroll
    for (int c = 0; c < 8; ++c) facc[c] = 0.0f;
    half2v a01 = {0, 0}, a23 = {0, 0}, a45 = {0, 0}, a67 = {0, 0};

#pragma unroll
    for (int i = 0; i < 4; ++i) {
#pragma unroll
        for (int j = 0; j < 4; ++j) {
            _Float16 wtdh = (_Float16)(wtv[i] * wdv[j]);
            half2v wtd2 = {wtdh, wtdh};
#pragma unroll
            for (int k = 0; k < 4; ++k) {
                int a = base + i * (4 * ND * NH * NW) + j * (4 * NH * NW) +
                        k * (4 * NW);
                H8 P;
                P.v = grid[a];
                half2v uw = wtd2 * whW2[k];
                a01 += P.h2[0] * uw;
                a23 += P.h2[1] * uw;
                a45 += P.h2[2] * uw;
                a67 += P.h2[3] * uw;
            }
        }
        if (i == 1 || i == 3) {
            facc[0] += (float)a01[0]; facc[1] += (float)a01[1];
            facc[2] += (float)a23[0]; facc[3] += (float)a23[1];
            facc[4] += (float)a45[0]; facc[5] += (float)a45[1];
            facc[6] += (float)a67[0]; facc[7] += (float)a67[1];
            a01 = (half2v){0, 0}; a23 = (half2v){0, 0};
            a45 = (half2v){0, 0}; a67 = (half2v){0, 0};
        }
    }

#pragma unroll
    for (int c = 0; c < 8; ++c) {
        facc[c] += __shfl_xor(facc[c], 4);
        facc[c] += __shfl_xor(facc[c], 8);
    }

    if (s < 4) {
        out[q * 8 + s * 2] = make_float4(facc[0], facc[1], facc[2], facc[3]);
        out[q * 8 + s * 2 + 1] = make_float4(facc[4], facc[5], facc[6], facc[7]);
    }
}

extern "C" void kernel_launch(void* const* d_in, const int* in_sizes, int n_in,
                              void* d_out, int out_size, void* d_ws, size_t ws_size,
                              hipStream_t stream) {
    const float* u = (const float*)d_in[0];
    const float* grid_f32 = (const float*)d_in[1];
    float4* out = (float4*)d_out;

    const size_t n_grid_floats = (size_t)NT * ND * NH * NW * NC;  // 1,048,576
    const size_t HG_BYTES = n_grid_floats * 2;                    // 2 MiB

    // workspace layout
    char* ws = (char*)d_ws;
    const size_t OFF_COUNT = HG_BYTES;                // 845*4 -> reserve 8KB
    const size_t OFF_OFFS = OFF_COUNT + 8192;         // 845*4 -> reserve 8KB
    const size_t OFF_CR = OFF_OFFS + 8192;            // 65536*4
    const size_t OFF_PERM = OFF_CR + (size_t)NB * 4;  // 65536*4
    const size_t NEED = OFF_PERM + (size_t)NB * 4;    // ~2.61 MB

    int cvt_blocks = (int)(n_grid_floats / 4 / 256);  // 1024

    if (ws_size >= NEED) {
        half4* hgrid = (half4*)ws;
        int* count = (int*)(ws + OFF_COUNT);
        int* offs = (int*)(ws + OFF_OFFS);
        unsigned* cellrank = (unsigned*)(ws + OFF_CR);
        int* perm = (int*)(ws + OFF_PERM);

        hipMemsetAsync(count, 0, 8192, stream);
        convert_fp16_kernel<<<cvt_blocks, 256, 0, stream>>>(
            (const float4*)grid_f32, hgrid);
        bin_count_kernel<<<NB / 256, 256, 0, stream>>>(
            (const float4*)u, count, cellrank);
        scan_kernel<<<1, 1024, 0, stream>>>(count, offs);
        scatter_kernel<<<NB / 256, 256, 0, stream>>>(cellrank, offs, perm);
        spline4d_binned_kernel<<<NCELLS, 512, 0, stream>>>(
            u, (const uint4*)hgrid, count, offs, perm, out);
    } else if (ws_size >= HG_BYTES) {
        half4* hgrid = (half4*)ws;
        convert_fp16_kernel<<<cvt_blocks, 256, 0, stream>>>(
            (const float4*)grid_f32, hgrid);
        int nblocks = NB * 16 / 256;
        spline4d_fp16_kernel<<<nblocks, 256, 0, stream>>>(
            u, (const half8*)hgrid, out);
    }
    // (ws is always >= 2 MiB in this harness; no f32 fallback needed beyond this)
}

// Round 10
// 78.166 us; speedup vs baseline: 1.1921x; 1.1921x over previous
//
#include <hip/hip_runtime.h>

#define NT 8
#define ND 16
#define NH 16
#define NW 16
#define NC 32
#define NB 65536
#define NCELLS (5 * 13 * 13)          // 845 span-base cells (t,d,h)
#define CHUNK 32
#define MAXCHUNKS (NCELLS + NB / CHUNK)   // 845 + 2048 = 2893

typedef __attribute__((ext_vector_type(8))) _Float16 half8;
typedef __attribute__((ext_vector_type(4))) _Float16 half4;
typedef __attribute__((ext_vector_type(2))) _Float16 half2v;

union H8 {
    half8 v;
    half2v h2[4];
};

// ---- shared span-base logic (IDENTICAL in binning + main) ----
template <int N>
__device__ __forceinline__ int span_base(float u) {
    float s = u * (float)(N - 1);
    float fi = fminf(fmaxf(floorf(s), 0.0f), (float)(N - 2));
    int i = (int)fi;
    return (i == 0) ? 0 : ((i == N - 2) ? (N - 4) : (i - 1));
}

// Span-based per-dim setup: span b..b+3 (in-bounds) + 4 weights with the
// linear-extrapolation padding folded in. Validated rounds 3-9 (absmax 7.8e-3).
template <int N>
__device__ __forceinline__ void dim_setup_span(float u, int& b, float w[4]) {
    float s = u * (float)(N - 1);
    float fi = fminf(fmaxf(floorf(s), 0.0f), (float)(N - 2));
    float t = s - fi;
    int i = (int)fi;
    float t2 = t * t, t3 = t2 * t;
    const float c6 = 1.0f / 6.0f;
    float w0 = (1.0f - 3.0f * t + 3.0f * t2 - t3) * c6;
    float w1 = (4.0f - 6.0f * t2 + 3.0f * t3) * c6;
    float w2 = (1.0f + 3.0f * t + 3.0f * t2 - 3.0f * t3) * c6;
    float w3 = t3 * c6;
    if (i == 0) {
        b = 0;
        w[0] = w1 + 2.0f * w0; w[1] = w2 - w0; w[2] = w3; w[3] = 0.0f;
    } else if (i == N - 2) {
        b = N - 4;
        w[0] = 0.0f; w[1] = w0; w[2] = w1 - w3; w[3] = w2 + 2.0f * w3;
    } else {
        b = i - 1;
        w[0] = w0; w[1] = w1; w[2] = w2; w[3] = w3;
    }
}

// ---- fused: f32->fp16 grid convert (blocks 0..1023) + cell count (1024..1279)
__global__ __launch_bounds__(256) void convert_count_kernel(
    const float4* __restrict__ g, half4* __restrict__ hg,
    const float4* __restrict__ u4, int* __restrict__ count,
    unsigned* __restrict__ cellrank) {
    int b = blockIdx.x;
    int t = threadIdx.x;
    if (b < 1024) {
        int i = b * 256 + t;
        float4 v = g[i];
        half4 h;
        h[0] = (_Float16)v.x;
        h[1] = (_Float16)v.y;
        h[2] = (_Float16)v.z;
        h[3] = (_Float16)v.w;
        hg[i] = h;
    } else {
        int q = (b - 1024) * 256 + t;
        float4 uu = u4[q];
        int bt = span_base<NT>(uu.x);
        int bd = span_base<ND>(uu.y);
        int bh = span_base<NH>(uu.z);
        int cell = (bt * 13 + bd) * 13 + bh;
        unsigned rank = (unsigned)atomicAdd(&count[cell], 1);
        cellrank[q] = ((unsigned)cell << 16) | rank;
    }
}

// ---- single-wave scan: offs (exclusive prefix of count) + chunk table ----
// 64 lanes, each serially owns ceil(845/64)=14 cells; register/shfl only.
__global__ __launch_bounds__(64) void scan_chunks_kernel(
    const int* __restrict__ count, int* __restrict__ offs,
    uint2* __restrict__ chunks, int* __restrict__ nchunks) {
    int lane = threadIdx.x;
    int c0 = lane * 14;
    int c1 = min(c0 + 14, NCELLS);

    int qsum = 0, csum = 0;
    for (int c = c0; c < c1; ++c) {
        int n = count[c];
        qsum += n;
        csum += (n + CHUNK - 1) / CHUNK;
    }
    // wave-wide exclusive scan (shfl_up over 64 lanes)
    int qv = qsum, cv = csum;
    for (int d = 1; d < 64; d <<= 1) {
        int tq = __shfl_up(qv, d);
        int tc = __shfl_up(cv, d);
        if (lane >= d) { qv += tq; cv += tc; }
    }
    int qo = qv - qsum;
    int co = cv - csum;

    for (int c = c0; c < c1; ++c) {
        int n = count[c];
        offs[c] = qo;
        int nch = (n + CHUNK - 1) / CHUNK;
        for (int k = 0; k < nch; ++k) {
            int len = min(CHUNK, n - k * CHUNK);
            uint2 rec;
            rec.x = (unsigned)(qo + k * CHUNK);
            rec.y = (unsigned)c | ((unsigned)len << 16);
            chunks[co + k] = rec;
        }
        qo += n;
        co += nch;
    }
    if (lane == 63) *nchunks = co;
}

__global__ __launch_bounds__(256) void scatter_kernel(
    const unsigned* __restrict__ cellrank, const int* __restrict__ offs,
    int* __restrict__ perm) {
    int q = blockIdx.x * blockDim.x + threadIdx.x;
    unsigned cr = cellrank[q];
    int cell = (int)(cr >> 16);
    int rank = (int)(cr & 0xffffu);
    perm[offs[cell] + rank] = q;
}

// ---- main: one block per <=32-query chunk; stage cell region to LDS ----
__global__ __launch_bounds__(512) void spline4d_chunk_kernel(
    const float* __restrict__ u, const uint4* __restrict__ hgrid,
    const uint2* __restrict__ chunks, const int* __restrict__ nchunks,
    const int* __restrict__ perm, float4* __restrict__ out) {
    if ((int)blockIdx.x >= *nchunks) return;

    __shared__ uint4 smem[4096];   // 64 KB: 64 rows x 1KB

    uint2 rec = chunks[blockIdx.x];
    int start = (int)rec.x;
    int cell = (int)(rec.y & 0xffffu);
    int len = (int)(rec.y >> 16);
    int bt = cell / 169;
    int r0 = cell - bt * 169;
    int bd = r0 / 13;
    int bh = r0 - bd * 13;

    // stage 64 rows (i,j,k), each 1KB (16 w-points x 64B) = 4096 uint4
    for (int idx = (int)threadIdx.x; idx < 4096; idx += 512) {
        int lrow = idx >> 6;
        int chunk = idx & 63;
        int i = lrow >> 4, j = (lrow >> 2) & 3, k = lrow & 3;
        int R = ((bt + i) * ND + (bd + j)) * NH + (bh + k);
        smem[idx] = hgrid[R * 64 + chunk];
    }
    __syncthreads();

    int slot = (int)threadIdx.x >> 4;
    int s = (int)threadIdx.x & 15;
    if (slot >= len) return;

    const half8* slds = reinterpret_cast<const half8*>(smem);
    int q = perm[start + slot];

    float4 uu = reinterpret_cast<const float4*>(u)[q];

    int xbt, xbd, xbh, bw;
    float wtv[4], wdv[4], whv[4], wwv[4];
    dim_setup_span<NT>(uu.x, xbt, wtv);
    dim_setup_span<ND>(uu.y, xbd, wdv);
    dim_setup_span<NH>(uu.z, xbh, whv);
    dim_setup_span<NW>(uu.w, bw, wwv);

    int wp = s >> 2;
    float wlane = (wp & 2) ? ((wp & 1) ? wwv[3] : wwv[2])
                           : ((wp & 1) ? wwv[1] : wwv[0]);

    half2v whW2[4];
#pragma unroll
    for (int k = 0; k < 4; ++k) {
        _Float16 h = (_Float16)(whv[k] * wlane);
        whW2[k][0] = h;
        whW2[k][1] = h;
    }

    float facc[8];
#pragma unroll
    for (int c = 0; c < 8; ++c) facc[c] = 0.0f;
    half2v a01 = {0, 0}, a23 = {0, 0}, a45 = {0, 0}, a67 = {0, 0};

    int lbase = (bw << 2) + s;

#pragma unroll
    for (int i = 0; i < 4; ++i) {
#pragma unroll
        for (int j = 0; j < 4; ++j) {
            _Float16 wtdh = (_Float16)(wtv[i] * wdv[j]);
            half2v wtd2 = {wtdh, wtdh};
#pragma unroll
            for (int k = 0; k < 4; ++k) {
                int lidx = ((i << 4) + (j << 2) + k) * 64 + lbase;
                H8 P;
                P.v = slds[lidx];
                half2v uw = wtd2 * whW2[k];
                a01 += P.h2[0] * uw;
                a23 += P.h2[1] * uw;
                a45 += P.h2[2] * uw;
                a67 += P.h2[3] * uw;
            }
        }
        if (i == 1 || i == 3) {
            facc[0] += (float)a01[0]; facc[1] += (float)a01[1];
            facc[2] += (float)a23[0]; facc[3] += (float)a23[1];
            facc[4] += (float)a45[0]; facc[5] += (float)a45[1];
            facc[6] += (float)a67[0]; facc[7] += (float)a67[1];
            a01 = (half2v){0, 0}; a23 = (half2v){0, 0};
            a45 = (half2v){0, 0}; a67 = (half2v){0, 0};
        }
    }

#pragma unroll
    for (int c = 0; c < 8; ++c) {
        facc[c] += __shfl_xor(facc[c], 4);
        facc[c] += __shfl_xor(facc[c], 8);
    }

    if (s < 4) {
        out[q * 8 + s * 2] = make_float4(facc[0], facc[1], facc[2], facc[3]);
        out[q * 8 + s * 2 + 1] = make_float4(facc[4], facc[5], facc[6], facc[7]);
    }
}

// ---- fallback: round-6 direct-gather fp16 kernel (passed, 52.5us) ----
__global__ __launch_bounds__(256) void convert_fp16_kernel(
    const float4* __restrict__ g, half4* __restrict__ hg) {
    int i = blockIdx.x * blockDim.x + threadIdx.x;
    float4 v = g[i];
    half4 h;
    h[0] = (_Float16)v.x;
    h[1] = (_Float16)v.y;
    h[2] = (_Float16)v.z;
    h[3] = (_Float16)v.w;
    hg[i] = h;
}

__global__ __launch_bounds__(256) void spline4d_fp16_kernel(
    const float* __restrict__ u, const half8* __restrict__ grid,
    float4* __restrict__ out) {
    int tid = blockIdx.x * blockDim.x + threadIdx.x;
    int q = tid >> 4;
    int s = tid & 15;

    float4 uu = reinterpret_cast<const float4*>(u)[q];

    int bt, bd, bh, bw;
    float wtv[4], wdv[4], whv[4], wwv[4];
    dim_setup_span<NT>(uu.x, bt, wtv);
    dim_setup_span<ND>(uu.y, bd, wdv);
    dim_setup_span<NH>(uu.z, bh, whv);
    dim_setup_span<NW>(uu.w, bw, wwv);

    int wp = s >> 2;
    float wlane = (wp & 2) ? ((wp & 1) ? wwv[3] : wwv[2])
                           : ((wp & 1) ? wwv[1] : wwv[0]);

    half2v whW2[4];
#pragma unroll
    for (int k = 0; k < 4; ++k) {
        _Float16 h = (_Float16)(whv[k] * wlane);
        whW2[k][0] = h;
        whW2[k][1] = h;
    }

    int base = ((((bt * ND + bd) * NH + bh) * NW + bw) << 2) + s;

    float facc[8];
#pragma unroll
    for (int c = 0; c < 8; ++c) facc[c] = 0.0f;
    half2v a01 = {0, 0}, a23 = {0, 0}, a45 = {0, 0}, a67 = {0, 0};

#pragma unroll
    for (int i = 0; i < 4; ++i) {
#pragma unroll
        for (int j = 0; j < 4; ++j) {
            _Float16 wtdh = (_Float16)(wtv[i] * wdv[j]);
            half2v wtd2 = {wtdh, wtdh};
#pragma unroll
            for (int k = 0; k < 4; ++k) {
                int a = base + i * (4 * ND * NH * NW) + j * (4 * NH * NW) +
                        k * (4 * NW);
                H8 P;
                P.v = grid[a];
                half2v uw = wtd2 * whW2[k];
                a01 += P.h2[0] * uw;
                a23 += P.h2[1] * uw;
                a45 += P.h2[2] * uw;
                a67 += P.h2[3] * uw;
            }
        }
        if (i == 1 || i == 3) {
            facc[0] += (float)a01[0]; facc[1] += (float)a01[1];
            facc[2] += (float)a23[0]; facc[3] += (float)a23[1];
            facc[4] += (float)a45[0]; facc[5] += (float)a45[1];
            facc[6] += (float)a67[0]; facc[7] += (float)a67[1];
            a01 = (half2v){0, 0}; a23 = (half2v){0, 0};
            a45 = (half2v){0, 0}; a67 = (half2v){0, 0};
        }
    }

#pragma unroll
    for (int c = 0; c < 8; ++c) {
        facc[c] += __shfl_xor(facc[c], 4);
        facc[c] += __shfl_xor(facc[c], 8);
    }

    if (s < 4) {
        out[q * 8 + s * 2] = make_float4(facc[0], facc[1], facc[2], facc[3]);
        out[q * 8 + s * 2 + 1] = make_float4(facc[4], facc[5], facc[6], facc[7]);
    }
}

extern "C" void kernel_launch(void* const* d_in, const int* in_sizes, int n_in,
                              void* d_out, int out_size, void* d_ws, size_t ws_size,
                              hipStream_t stream) {
    const float* u = (const float*)d_in[0];
    const float* grid_f32 = (const float*)d_in[1];
    float4* out = (float4*)d_out;

    const size_t n_grid_floats = (size_t)NT * ND * NH * NW * NC;  // 1,048,576
    const size_t HG_BYTES = n_grid_floats * 2;                    // 2 MiB

    // workspace layout
    char* ws = (char*)d_ws;
    const size_t OFF_COUNT = HG_BYTES;                 // 845*4 -> reserve 8KB
    const size_t OFF_OFFS = OFF_COUNT + 8192;          // 845*4 -> reserve 8KB
    const size_t OFF_CR = OFF_OFFS + 8192;             // 65536*4
    const size_t OFF_PERM = OFF_CR + (size_t)NB * 4;   // 65536*4
    const size_t OFF_CHUNKS = OFF_PERM + (size_t)NB * 4;   // 2893*8 -> 24KB
    const size_t OFF_NCH = OFF_CHUNKS + 24576;         // 4B (pad 256)
    const size_t NEED = OFF_NCH + 256;                 // ~2.66 MB

    if (ws_size >= NEED) {
        half4* hgrid = (half4*)ws;
        int* count = (int*)(ws + OFF_COUNT);
        int* offs = (int*)(ws + OFF_OFFS);
        unsigned* cellrank = (unsigned*)(ws + OFF_CR);
        int* perm = (int*)(ws + OFF_PERM);
        uint2* chunks = (uint2*)(ws + OFF_CHUNKS);
        int* nchunks = (int*)(ws + OFF_NCH);

        hipMemsetAsync(count, 0, 8192, stream);
        convert_count_kernel<<<1024 + NB / 256, 256, 0, stream>>>(
            (const float4*)grid_f32, hgrid, (const float4*)u, count, cellrank);
        scan_chunks_kernel<<<1, 64, 0, stream>>>(count, offs, chunks, nchunks);
        scatter_kernel<<<NB / 256, 256, 0, stream>>>(cellrank, offs, perm);
        spline4d_chunk_kernel<<<MAXCHUNKS, 512, 0, stream>>>(
            u, (const uint4*)hgrid, chunks, nchunks, perm, out);
    } else if (ws_size >= HG_BYTES) {
        half4* hgrid = (half4*)ws;
        int cvt_blocks = (int)(n_grid_floats / 4 / 256);  // 1024
        convert_fp16_kernel<<<cvt_blocks, 256, 0, stream>>>(
            (const float4*)grid_f32, hgrid);
        int nblocks = NB * 16 / 256;
        spline4d_fp16_kernel<<<nblocks, 256, 0, stream>>>(
            u, (const half8*)hgrid, out);
    }
}